// Round 4
// baseline (79.105 us; speedup 1.0000x reference)
//
#include <hip/hip_runtime.h>

// x: (32, 3, 1024, 1024) f32, l: (32,2) i32
// out = [ full: 32*3*1024*1024 f32 , patch: 32*3*128*128 f32 ]
//
// window rows = l0 - 193 + i (i in [0,128)), cols = l1 - 193 + j (j in [0,128))
// patch[b,c,i,j] = valid ? x[b,c,row,col] : 0
// full = x masked to the valid window, 0 elsewhere.

#define FULL_ELEMS  (32L * 3 * 1024 * 1024)   // 100663296

// full: 1 block = 4 consecutive image rows (same (b,c) image since 1024 rows/img).
// Thread t stores float4 #t of each of the 4 rows -> 64 B/thread, scalar control.
#define FULL_BLOCKS 24576
// patch: 393216 float4s, one per thread -> 1536 blocks.
#define PATCH_BLOCKS 1536

__global__ __launch_bounds__(256) void retina_fused(const float* __restrict__ x,
                                                    const int* __restrict__ l,
                                                    float* __restrict__ full,
                                                    float* __restrict__ patch) {
    int bid = blockIdx.x;
    if (bid < FULL_BLOCKS) {
        // ---- full: 4 rows per block, all row control scalar ----
        int row0 = bid << 2;                 // first global row (scalar)
        int r0   = row0 & 1023;              // row within image (scalar)
        int bc   = row0 >> 10;               // (b,c) in [0,96)  (scalar)
        int b    = bc / 3;                   // scalar magic-mul
        int l0 = l[2 * b];                   // scalar loads
        int l1 = l[2 * b + 1];
        int i0 = r0 - (l0 - 193);            // patch row idx of row0 (scalar)

        const float4* xbase = (const float4*)(x    + ((long)row0 << 10));
        float4*       fbase = (float4*)      (full + ((long)row0 << 10));
        int w4 = threadIdx.x;
        int jb = (w4 << 2) - (l1 - 193);     // patch col of elem 0 (per-thread)
        bool colin = (jb >= -3 && jb < 128); // this float4 overlaps col window

#pragma unroll
        for (int k = 0; k < 4; ++k) {
            float4 o = make_float4(0.f, 0.f, 0.f, 0.f);
            if ((unsigned)(i0 + k) < 128u && colin) {   // row test scalar
                float4 v = xbase[(k << 8) + w4];
                o.x = ((unsigned)(jb + 0) < 128u) ? v.x : 0.f;
                o.y = ((unsigned)(jb + 1) < 128u) ? v.y : 0.f;
                o.z = ((unsigned)(jb + 2) < 128u) ? v.z : 0.f;
                o.w = ((unsigned)(jb + 3) < 128u) ? v.w : 0.f;
            }
            fbase[(k << 8) + w4] = o;
        }
    } else {
        // ---- patch: one float4 per thread (R0/R2-verified logic) ----
        int tid = (bid - FULL_BLOCKS) * 256 + (int)threadIdx.x;
        int j4 = tid & 31;                   // col float4 (128/4)
        int i  = (tid >> 5) & 127;           // patch row
        int bc = tid >> 12;                  // (b,c) in [0,96)
        int b  = bc / 3;
        int l0 = l[2 * b];
        int l1 = l[2 * b + 1];
        int r  = l0 - 193 + i;
        float o[4] = {0.f, 0.f, 0.f, 0.f};
        if ((unsigned)r < 1024u) {
            const float* xrow = x + (((long)bc << 10) + r) * 1024;
            int wbase = l1 - 193 + (j4 << 2);
#pragma unroll
            for (int e = 0; e < 4; ++e) {
                int w = wbase + e;
                if ((unsigned)w < 1024u) o[e] = xrow[w];
            }
        }
        *(float4*)(patch + ((long)tid << 2)) = make_float4(o[0], o[1], o[2], o[3]);
    }
}

extern "C" void kernel_launch(void* const* d_in, const int* in_sizes, int n_in,
                              void* d_out, int out_size, void* d_ws, size_t ws_size,
                              hipStream_t stream) {
    const float* x = (const float*)d_in[0];
    const int*   l = (const int*)d_in[1];
    float* full  = (float*)d_out;
    float* patch = full + FULL_ELEMS;
    retina_fused<<<FULL_BLOCKS + PATCH_BLOCKS, 256, 0, stream>>>(x, l, full, patch);
}